// Round 3
// baseline (412.719 us; speedup 1.0000x reference)
//
#include <hip/hip_runtime.h>
#include <hip/hip_bf16.h>
#include <stdint.h>

// ---------- types / helpers ----------
typedef float f32x4 __attribute__((ext_vector_type(4)));
typedef __bf16 bf16x8 __attribute__((ext_vector_type(8)));
typedef unsigned short ushort8 __attribute__((ext_vector_type(8)));

__device__ __forceinline__ float bf2f(unsigned short u) {
    unsigned int x = ((unsigned int)u) << 16;
    return __builtin_bit_cast(float, x);
}
__device__ __forceinline__ unsigned short f2bf(float f) {
    unsigned int x = __builtin_bit_cast(unsigned int, f);
    unsigned int lsb = (x >> 16) & 1u;
    x += 0x7fffu + lsb;            // round-to-nearest-even
    return (unsigned short)(x >> 16);
}

#define GLL16(gptr, lptr)                                                      \
    __builtin_amdgcn_global_load_lds(                                          \
        (const __attribute__((address_space(1))) void*)(gptr),                 \
        (__attribute__((address_space(3))) void*)(lptr), 16, 0, 0)

// counted vmcnt wait: retire old VMEM ops, keep the current region's in flight
#define VMWAIT(N)                                                              \
    do { asm volatile("s_waitcnt vmcnt(" #N ")" ::: "memory"); } while (0)

// ---------- fp32 -> bf16 convert, all 4 weight matrices in one launch ----------
__global__ __launch_bounds__(256) void cvt4_kernel(
    const float* __restrict__ w0, const float* __restrict__ w1,
    const float* __restrict__ w2, const float* __restrict__ w3,
    unsigned short* __restrict__ dst)
{
    const int i = blockIdx.x * 256 + threadIdx.x;   // 0..196607
    const float* s; int off;
    if      (i <  49152) { s = w0; off = 0; }
    else if (i <  65536) { s = w1; off = 49152; }
    else if (i < 131072) { s = w2; off = 65536; }
    else                 { s = w3; off = 131072; }
    f32x4 v = ((const f32x4*)s)[i - off];
    ushort4 o;
    o.x = f2bf(v.x); o.y = f2bf(v.y); o.z = f2bf(v.z); o.w = f2bf(v.w);
    ((ushort4*)dst)[i] = o;
}

// ---------- LayerNorm (LN1): fp32 in -> bf16 out, one wave per token ----------
__global__ __launch_bounds__(256) void ln_kernel(
    const float* __restrict__ x, const float* __restrict__ g,
    const float* __restrict__ b, unsigned short* __restrict__ y)
{
    const int lane = threadIdx.x & 63, wave = threadIdx.x >> 6;
    const size_t tok = (size_t)blockIdx.x * 4 + wave;
    f32x4 v = *(const f32x4*)(x + tok * 256 + lane * 4);
    float s = v.x + v.y + v.z + v.w;
    float q = v.x * v.x + v.y * v.y + v.z * v.z + v.w * v.w;
#pragma unroll
    for (int o = 32; o; o >>= 1) {
        s += __shfl_xor(s, o, 64);
        q += __shfl_xor(q, o, 64);
    }
    float mean = s * (1.f / 256.f);
    float var  = q * (1.f / 256.f) - mean * mean;
    float rstd = rsqrtf(var + 1e-5f);
    f32x4 gr = *(const f32x4*)(g + lane * 4);
    f32x4 br = *(const f32x4*)(b + lane * 4);
    ushort4 o4;
    o4.x = f2bf((v.x - mean) * rstd * gr.x + br.x);
    o4.y = f2bf((v.y - mean) * rstd * gr.y + br.y);
    o4.z = f2bf((v.z - mean) * rstd * gr.z + br.z);
    o4.w = f2bf((v.w - mean) * rstd * gr.w + br.w);
    *(ushort4*)(y + tok * 256 + lane * 4) = o4;
}

// ---------- GEMM (phase A: qkv / proj) ----------
template <int RELU, int HASRES, int OUTF32>
__global__ __launch_bounds__(256) void gemm_bt(
    const unsigned short* __restrict__ A,    // [M,K] bf16
    const unsigned short* __restrict__ W,    // [N,K] bf16
    const float* __restrict__ bias,          // [N]   fp32
    const float* res,                        // [M,N] fp32 or null
    void* Cv,                                // [M,N] bf16 or fp32
    int M, int N, int K, int nby)
{
    __shared__ __align__(16) unsigned short As[128 * 64];
    __shared__ __align__(16) unsigned short Bs[128 * 64];

    const int t    = threadIdx.x;
    const int id   = blockIdx.x;
    const int xcd  = id & 7;
    const int sl   = id >> 3;
    const int by   = sl % nby;
    const int bx   = (sl / nby) * 8 + xcd;
    const int m0   = bx * 128;
    const int n0   = by * 128;
    const int lane = t & 63;
    const int wave = t >> 6;
    const int wm = wave & 1, wn = wave >> 1;
    const int lr = lane & 15, kc = lane >> 4;

    f32x4 acc[4][4] = {};

    const int rA   = t >> 3;                       // 0..31
    const int gcol = ((t & 7) ^ (rA & 7)) * 8;
    const unsigned short* gA = A + (size_t)(m0 + rA) * K + gcol;
    const unsigned short* gB = W + (size_t)(n0 + rA) * K + gcol;

    for (int k0 = 0; k0 < K; k0 += 64) {
#pragma unroll
        for (int w = 0; w < 4; ++w) {
            GLL16(gA + (size_t)(w * 32) * K + k0, &As[(w * 256 + t) * 8]);
            GLL16(gB + (size_t)(w * 32) * K + k0, &Bs[(w * 256 + t) * 8]);
        }
        __syncthreads();

#pragma unroll
        for (int hh = 0; hh < 2; ++hh) {
            bf16x8 af[4], bf[4];
#pragma unroll
            for (int i = 0; i < 4; ++i) {
                const int ra = wm * 64 + i * 16 + lr;
                const int rb = wn * 64 + i * 16 + lr;
                af[i] = *(const bf16x8*)&As[ra * 64 + ((hh * 4 + kc) ^ (ra & 7)) * 8];
                bf[i] = *(const bf16x8*)&Bs[rb * 64 + ((hh * 4 + kc) ^ (rb & 7)) * 8];
            }
#pragma unroll
            for (int i = 0; i < 4; ++i)
#pragma unroll
                for (int j = 0; j < 4; ++j)
                    acc[i][j] = __builtin_amdgcn_mfma_f32_16x16x32_bf16(
                        af[i], bf[j], acc[i][j], 0, 0, 0);
        }
        __syncthreads();
    }

    float* Cf = (float*)Cv;
    unsigned short* Cb = (unsigned short*)Cv;
    const int row0 = m0 + wm * 64;
    const int col0 = n0 + wn * 64;
    const int cl = lane & 15;
    const int rq = (lane >> 4) * 4;
#pragma unroll
    for (int i = 0; i < 4; ++i) {
#pragma unroll
        for (int j = 0; j < 4; ++j) {
            const int col = col0 + j * 16 + cl;
            const float bv = bias[col];
#pragma unroll
            for (int r = 0; r < 4; ++r) {
                const int row = row0 + i * 16 + rq + r;
                float v = acc[i][j][r] + bv;
                if (RELU) v = fmaxf(v, 0.f);
                const size_t o = (size_t)row * N + col;
                if (HASRES) v += res[o];
                if (OUTF32) Cf[o] = v;
                else        Cb[o] = f2bf(v);
            }
        }
    }
}

// ---------- Per-token head-mix attention (bf16 in/out), unchanged ----------
__global__ __launch_bounds__(256) void attn_headmix(
    const unsigned short* __restrict__ qkv,  // [T,768] bf16
    unsigned short* __restrict__ out,        // [T,256] bf16
    int T)
{
    const int lane = threadIdx.x & 63, wave = threadIdx.x >> 6;
    const int tok = blockIdx.x * 4 + wave;
    if (tok >= T) return;
    const unsigned short* base = qkv + (size_t)tok * 768;
    const int h = lane >> 3, g = lane & 7;

    float s = 0.f;
#pragma unroll
    for (int d8 = 0; d8 < 4; ++d8) {
        ushort4 qa = *(const ushort4*)(base + h * 32 + d8 * 8);
        ushort4 qb = *(const ushort4*)(base + h * 32 + d8 * 8 + 4);
        ushort4 ka = *(const ushort4*)(base + 256 + g * 32 + d8 * 8);
        ushort4 kb = *(const ushort4*)(base + 256 + g * 32 + d8 * 8 + 4);
        s += bf2f(qa.x) * bf2f(ka.x) + bf2f(qa.y) * bf2f(ka.y)
           + bf2f(qa.z) * bf2f(ka.z) + bf2f(qa.w) * bf2f(ka.w)
           + bf2f(qb.x) * bf2f(kb.x) + bf2f(qb.y) * bf2f(kb.y)
           + bf2f(qb.z) * bf2f(kb.z) + bf2f(qb.w) * bf2f(kb.w);
    }
    s *= 0.17677669529663687f;

    float mx = s;
#pragma unroll
    for (int o = 1; o < 8; o <<= 1) mx = fmaxf(mx, __shfl_xor(mx, o, 64));
    float e = __expf(s - mx);
    float sum = e;
#pragma unroll
    for (int o = 1; o < 8; o <<= 1) sum += __shfl_xor(sum, o, 64);
    const float a = e / sum;

    float o0 = 0.f, o1 = 0.f, o2 = 0.f, o3 = 0.f;
#pragma unroll
    for (int gg = 0; gg < 8; ++gg) {
        const float ag = __shfl(a, (lane & 56) | gg, 64);
        ushort4 vv = *(const ushort4*)(base + 512 + gg * 32 + g * 4);
        o0 += ag * bf2f(vv.x);
        o1 += ag * bf2f(vv.y);
        o2 += ag * bf2f(vv.z);
        o3 += ag * bf2f(vv.w);
    }
    ushort4 ov;
    ov.x = f2bf(o0); ov.y = f2bf(o1); ov.z = f2bf(o2); ov.w = f2bf(o3);
    *(ushort4*)(out + (size_t)tok * 256 + lane * 4) = ov;
}

// ---------- Fused LN2 + FFN1(relu) + FFN2 + residual, in-place on xo ----------
// ROUND 3: m201-style fine phase split. R2 proved counted-vmcnt alone is null
// (m218's result reproduced): the coarse monolithic region left both
// waves/SIMD bursting the same pipe. Each region now = 4 MFMA phases of
// 16 mfma: {reads (+stage), s_barrier, lgkmcnt(0), sched_barrier, setprio,
// 16 mfma, setprio, s_barrier}. Counted vmcnt(9) twice per region.
// FIFO ledger (steady, entering region hc): [W1(hc+1)4][b(hc+1)1][W2(hc)4].
//   P1: stage W1(hc+2) -> 13 -> VMWAIT(9) retires W1(hc+1).
//   P2: load b(hc+2). HSTORE: compiler waits b(hc+1) (vmcnt(9), exact).
//   P3: stage W2(hc+1) -> 13 -> VMWAIT(9) retires W2(hc).
// Tails: region0 P1=5; region14 P1=5,P3=4; region15=0. All WAR hazards fenced
// by >=2 phase barriers between a buffer's readers and its next writer.
__global__ __launch_bounds__(512, 2) void ffn_fused(
    float* xo,                               // [M,256] fp32, read + written
    const float* __restrict__ ln2_g, const float* __restrict__ ln2_b,
    const unsigned short* __restrict__ w1,   // [1024,256] bf16
    const float* __restrict__ b1p,           // [1024]
    const unsigned short* __restrict__ w2,   // [256,1024] bf16
    const float* __restrict__ b2p)           // [256]
{
    __shared__ __align__(16) unsigned short U[32768];      // 64 KB: As, then W1b|W2b
    __shared__ __align__(16) unsigned short W1a[16384];    // 32 KB
    __shared__ __align__(16) unsigned short W2a[16384];    // 32 KB
    __shared__ __align__(16) unsigned short Hs[2][8192];   // 2 x 16 KB, swizzled

    unsigned short* const W1b = U;
    unsigned short* const W2b = U + 16384;

    const int t = threadIdx.x;               // 0..511
    const int lane = t & 63, wave = t >> 6;
    const int m0 = blockIdx.x * 128;
    const int lr = lane & 15, kc = lane >> 4;
    const int cl = lane & 15, rq = (lane >> 4) * 4;
    const int wm = wave & 1, wn = wave >> 1; // wn in 0..3

    // staging index precompute (j-invariant parts)
    const int r1b = t >> 5;                  // W1 row base 0..15
    const int sc1 = t & 31;
    const int gc1 = (sc1 & ~7) | ((sc1 & 7) ^ (r1b & 7));
    const int r2b = t >> 3;                  // W2 row base 0..63
    const int gc2 = (t & 7) ^ (r2b & 7);

    #define STAGE_W1(hp, W1t)                                                  \
        do {                                                                   \
            _Pragma("unroll")                                                  \
            for (int j = 0; j < 4; ++j)                                        \
                GLL16(w1 + (size_t)((hp) * 64 + j * 16 + r1b) * 256 + gc1 * 8, \
                      &(W1t)[(j * 512 + t) * 8]);                              \
        } while (0)
    #define STAGE_W2(hp, W2t)                                                  \
        do {                                                                   \
            _Pragma("unroll")                                                  \
            for (int j = 0; j < 4; ++j)                                        \
                GLL16(w2 + (size_t)(j * 64 + r2b) * 1024 + (hp) * 64 + gc2 * 8,\
                      &(W2t)[(j * 512 + t) * 8]);                              \
        } while (0)

    STAGE_W1(0, W1a);
    STAGE_W2(0, W2a);
    f32x4 bvc = *(const f32x4*)(b1p + wn * 16 + rq);           // bias(0)
    f32x4 bvn;

    // ---- phase 0: LN2 of the 128-row tile -> bf16 As in U (swizzled) ----
    {
        const int row0 = t >> 2;             // 0..127
        const int seg  = t & 3;              // 64-float segment
        const float* xrp = xo + (size_t)(m0 + row0) * 256 + seg * 64;
        f32x4 xv[16];
#pragma unroll
        for (int i = 0; i < 16; ++i) xv[i] = ((const f32x4*)xrp)[i];
        float s = 0.f, q = 0.f;
#pragma unroll
        for (int i = 0; i < 16; ++i) {
            s += xv[i].x + xv[i].y + xv[i].z + xv[i].w;
            q += xv[i].x * xv[i].x + xv[i].y * xv[i].y
               + xv[i].z * xv[i].z + xv[i].w * xv[i].w;
        }
        s += __shfl_xor(s, 1, 64); q += __shfl_xor(q, 1, 64);
        s += __shfl_xor(s, 2, 64); q += __shfl_xor(q, 2, 64);
        const float mean = s * (1.f / 256.f);
        const float rstd = rsqrtf(q * (1.f / 256.f) - mean * mean + 1e-5f);
#pragma unroll
        for (int c8 = 0; c8 < 8; ++c8) {
            const f32x4 g0 = ((const f32x4*)(ln2_g + seg * 64 + c8 * 8))[0];
            const f32x4 g1 = ((const f32x4*)(ln2_g + seg * 64 + c8 * 8))[1];
            const f32x4 bb0 = ((const f32x4*)(ln2_b + seg * 64 + c8 * 8))[0];
            const f32x4 bb1 = ((const f32x4*)(ln2_b + seg * 64 + c8 * 8))[1];
            const f32x4 a0 = xv[c8 * 2], a1 = xv[c8 * 2 + 1];
            ushort8 o;
            o[0] = f2bf((a0.x - mean) * rstd * g0.x + bb0.x);
            o[1] = f2bf((a0.y - mean) * rstd * g0.y + bb0.y);
            o[2] = f2bf((a0.z - mean) * rstd * g0.z + bb0.z);
            o[3] = f2bf((a0.w - mean) * rstd * g0.w + bb0.w);
            o[4] = f2bf((a1.x - mean) * rstd * g1.x + bb1.x);
            o[5] = f2bf((a1.y - mean) * rstd * g1.y + bb1.y);
            o[6] = f2bf((a1.z - mean) * rstd * g1.z + bb1.z);
            o[7] = f2bf((a1.w - mean) * rstd * g1.w + bb1.w);
            const int gc = seg * 8 + c8;     // global chunk 0..31
            const int sc = (gc & ~7) | ((gc & 7) ^ (row0 & 7));
            *(ushort8*)&U[row0 * 256 + sc * 8] = o;
        }
    }
    __syncthreads();   // As ready; W(0)/bias(0) landed (full drain, prologue only)

    // ---- register-cache this wave's A fragments (rows wm*64..+63, all K) ----
    bf16x8 afr[4][8];
#pragma unroll
    for (int i = 0; i < 4; ++i) {
        const int ra = wm * 64 + i * 16 + lr;
#pragma unroll
        for (int ks = 0; ks < 8; ++ks) {
            const int c = ks * 4 + kc;
            afr[i][ks] = *(const bf16x8*)
                &U[ra * 256 + ((c & ~7) | ((c & 7) ^ (ra & 7))) * 8];
        }
    }
    __syncthreads();   // all waves done reading U -> it becomes W buffer B

    f32x4 acc[4][4] = {};                    // out tile: rows wm*64, cols wn*64

    // ---- phase macros (m201 pattern) ----
    #define PHASE_H(W1c, ksb)                                                  \
        do {                                                                   \
            bf16x8 bfr_[4];                                                    \
            _Pragma("unroll")                                                  \
            for (int kk = 0; kk < 4; ++kk) {                                   \
                const int c = ((ksb) + kk) * 4 + kc;                           \
                const int rb = wn * 16 + lr;                                   \
                bfr_[kk] = *(const bf16x8*)                                    \
                    &(W1c)[rb * 256 + ((c & ~7) | ((c & 7) ^ (rb & 7))) * 8];  \
            }                                                                  \
            __builtin_amdgcn_s_barrier();                                      \
            asm volatile("s_waitcnt lgkmcnt(0)" ::: "memory");                 \
            __builtin_amdgcn_sched_barrier(0);                                 \
            __builtin_amdgcn_s_setprio(1);                                     \
            _Pragma("unroll")                                                  \
            for (int kk = 0; kk < 4; ++kk)                                     \
                _Pragma("unroll")                                              \
                for (int i = 0; i < 4; ++i)                                    \
                    acch[i] = __builtin_amdgcn_mfma_f32_16x16x32_bf16(         \
                        bfr_[kk], afr[i][(ksb) + kk], acch[i], 0, 0, 0);       \
            __builtin_amdgcn_s_setprio(0);                                     \
            __builtin_amdgcn_s_barrier();                                      \
        } while (0)

    #define PHASE_O(W2c, Hbuf, ksel)                                           \
        do {                                                                   \
            const int c = (ksel) * 4 + kc;                                     \
            bf16x8 bw_[4], ah_[4];                                             \
            _Pragma("unroll")                                                  \
            for (int j = 0; j < 4; ++j) {                                      \
                const int rb = wn * 64 + j * 16 + lr;                          \
                bw_[j] = *(const bf16x8*)                                      \
                    &(W2c)[rb * 64 + ((c ^ (rb & 7)) * 8)];                    \
            }                                                                  \
            _Pragma("unroll")                                                  \
            for (int i = 0; i < 4; ++i) {                                      \
                const int ra = wm * 64 + i * 16 + lr;                          \
                ah_[i] = *(const bf16x8*)                                      \
                    &(Hbuf)[ra * 64 + ((c ^ (ra & 7)) * 8)];                   \
            }                                                                  \
            __builtin_amdgcn_s_barrier();                                      \
            asm volatile("s_waitcnt lgkmcnt(0)" ::: "memory");                 \
            __builtin_amdgcn_sched_barrier(0);                                 \
            __builtin_amdgcn_s_setprio(1);                                     \
            _Pragma("unroll")                                                  \
            for (int i = 0; i < 4; ++i)                                        \
                _Pragma("unroll")                                              \
                for (int j = 0; j < 4; ++j)                                    \
                    acc[i][j] = __builtin_amdgcn_mfma_f32_16x16x32_bf16(       \
                        ah_[i], bw_[j], acc[i][j], 0, 0, 0);                   \
            __builtin_amdgcn_s_setprio(0);                                     \
            __builtin_amdgcn_s_barrier();                                      \
        } while (0)

    #define HSTORE(bv, Hbuf)                                                   \
        do {                                                                   \
            const int sbase = wn * 2 + (rq >> 3);                              \
            _Pragma("unroll")                                                  \
            for (int i = 0; i < 4; ++i) {                                      \
                const int tok = wm * 64 + i * 16 + cl;                         \
                ushort4 o;                                                     \
                o.x = f2bf(fmaxf(acch[i][0] + (bv).x, 0.f));                   \
                o.y = f2bf(fmaxf(acch[i][1] + (bv).y, 0.f));                   \
                o.z = f2bf(fmaxf(acch[i][2] + (bv).z, 0.f));                   \
                o.w = f2bf(fmaxf(acch[i][3] + (bv).w, 0.f));                   \
                *(ushort4*)&(Hbuf)[tok * 64 + ((sbase ^ (tok & 7)) * 8)        \
                                   + (rq & 4)] = o;                            \
            }                                                                  \
        } while (0)

    // ---- region -1: H(0) only ----
    STAGE_W1(1, W1b);
    {
        f32x4 acch[4] = {};
        PHASE_H(W1a, 0);
        bvn = *(const f32x4*)(b1p + 1 * 64 + wn * 16 + rq);
        PHASE_H(W1a, 4);
        HSTORE(bvc, Hs[0]);
    }
    bvc = bvn;

    // ---- region 0: H(1), O(0) ----
    STAGE_W1(2, W1a);
    VMWAIT(5);
    {
        f32x4 acch[4] = {};
        PHASE_H(W1b, 0);
        bvn = *(const f32x4*)(b1p + 2 * 64 + wn * 16 + rq);
        PHASE_H(W1b, 4);
        HSTORE(bvc, Hs[1]);
    }
    STAGE_W2(1, W2b);
    VMWAIT(9);
    PHASE_O(W2a, Hs[0], 0);
    PHASE_O(W2a, Hs[0], 1);
    bvc = bvn;

    // ---- regions 1..13 (steady state) ----
    for (int hc = 1; hc <= 13; ++hc) {
        unsigned short* const w1dst = (hc & 1) ? W1b : W1a;
        unsigned short* const w2dst = (hc & 1) ? W2a : W2b;
        unsigned short* const w1src = (hc & 1) ? W1a : W1b;
        unsigned short* const w2src = (hc & 1) ? W2b : W2a;
        unsigned short* const hdst = Hs[(hc + 1) & 1];
        unsigned short* const hsrc = Hs[hc & 1];
        STAGE_W1(hc + 2, w1dst);
        VMWAIT(9);
        {
            f32x4 acch[4] = {};
            PHASE_H(w1src, 0);
            bvn = *(const f32x4*)(b1p + (hc + 2) * 64 + wn * 16 + rq);
            PHASE_H(w1src, 4);
            HSTORE(bvc, hdst);
        }
        STAGE_W2(hc + 1, w2dst);
        VMWAIT(9);
        PHASE_O(w2src, hsrc, 0);
        PHASE_O(w2src, hsrc, 1);
        bvc = bvn;
    }

    // ---- region 14: H(15), O(14) ----
    VMWAIT(5);
    {
        f32x4 acch[4] = {};
        PHASE_H(W1b, 0);
        PHASE_H(W1b, 4);
        HSTORE(bvc, Hs[1]);
    }
    STAGE_W2(15, W2b);
    VMWAIT(4);
    PHASE_O(W2a, Hs[0], 0);
    PHASE_O(W2a, Hs[0], 1);

    // ---- region 15: O(15) only ----
    VMWAIT(0);
    PHASE_O(W2b, Hs[1], 0);
    PHASE_O(W2b, Hs[1], 1);

    // ---- epilogue: + b2 + residual(xo), write fp32 in place ----
    const int rqe = (lane >> 4) * 4;
#pragma unroll
    for (int i = 0; i < 4; ++i)
#pragma unroll
        for (int j = 0; j < 4; ++j) {
            const int col = wn * 64 + j * 16 + cl;
            const float bv = b2p[col];
#pragma unroll
            for (int r = 0; r < 4; ++r) {
                const int row = m0 + wm * 64 + i * 16 + rqe + r;
                const size_t o = (size_t)row * 256 + col;
                xo[o] = acc[i][j][r] + bv + xo[o];
            }
        }
    #undef STAGE_W1
    #undef STAGE_W2
    #undef PHASE_H
    #undef PHASE_O
    #undef HSTORE
}

// ---------- launch ----------
// fp32 I/O, bf16 internal, fp32 residual trunk on d_out.
// ws layout (ushort elems): weights [0,786432); xn [1M,17M); att [17M,33M);
// qkvb [33M,81M).
extern "C" void kernel_launch(void* const* d_in, const int* in_sizes, int n_in,
                              void* d_out, int out_size, void* d_ws, size_t ws_size,
                              hipStream_t stream)
{
    const float* x      = (const float*)d_in[0];
    const float* ln1_g  = (const float*)d_in[1];
    const float* ln1_b  = (const float*)d_in[2];
    const float* qkv_w  = (const float*)d_in[3];
    const float* qkv_b  = (const float*)d_in[4];
    const float* proj_w = (const float*)d_in[5];
    const float* proj_b = (const float*)d_in[6];
    const float* ln2_g  = (const float*)d_in[7];
    const float* ln2_b  = (const float*)d_in[8];
    const float* ffn_w1 = (const float*)d_in[9];
    const float* ffn_b1 = (const float*)d_in[10];
    const float* ffn_w2 = (const float*)d_in[11];
    const float* ffn_b2 = (const float*)d_in[12];
    float* xo = (float*)d_out;            // fp32 trunk + final out

    const int M = 65536;
    const size_t MEG = 1024 * 1024;
    unsigned short* ws = (unsigned short*)d_ws;
    unsigned short* qkv_wb  = ws;                   // 196608
    unsigned short* proj_wb = ws + 196608;          // 65536
    unsigned short* ffn_w1b = ws + 262144;          // 262144
    unsigned short* ffn_w2b = ws + 524288;          // 262144
    unsigned short* xn   = ws + 1 * MEG;            // [M,256]
    unsigned short* att  = ws + 17 * MEG;           // [M,256]
    unsigned short* qkvb = ws + 33 * MEG;           // [M,768]

    cvt4_kernel<<<768, 256, 0, stream>>>(qkv_w, proj_w, ffn_w1, ffn_w2, ws);

    ln_kernel<<<M / 4, 256, 0, stream>>>(x, ln1_g, ln1_b, xn);
    gemm_bt<0, 0, 0><<<3072, 256, 0, stream>>>(
        xn, qkv_wb, qkv_b, nullptr, qkvb, M, 768, 256, 6);
    attn_headmix<<<M / 4, 256, 0, stream>>>(qkvb, att, M);
    gemm_bt<0, 1, 1><<<1024, 256, 0, stream>>>(
        att, proj_wb, proj_b, x, xo, M, 256, 256, 2);
    ffn_fused<<<M / 128, 512, 0, stream>>>(
        xo, ln2_g, ln2_b, ffn_w1b, ffn_b1, ffn_w2b, ffn_b2);
}

// Round 4
// 343.598 us; speedup vs baseline: 1.2012x; 1.2012x over previous
//
#include <hip/hip_runtime.h>
#include <hip/hip_bf16.h>
#include <stdint.h>

// ---------- types / helpers ----------
typedef float f32x4 __attribute__((ext_vector_type(4)));
typedef __bf16 bf16x8 __attribute__((ext_vector_type(8)));
typedef unsigned short ushort8 __attribute__((ext_vector_type(8)));

__device__ __forceinline__ float bf2f(unsigned short u) {
    unsigned int x = ((unsigned int)u) << 16;
    return __builtin_bit_cast(float, x);
}
__device__ __forceinline__ unsigned short f2bf(float f) {
    unsigned int x = __builtin_bit_cast(unsigned int, f);
    unsigned int lsb = (x >> 16) & 1u;
    x += 0x7fffu + lsb;            // round-to-nearest-even
    return (unsigned short)(x >> 16);
}

#define GLL16(gptr, lptr)                                                      \
    __builtin_amdgcn_global_load_lds(                                          \
        (const __attribute__((address_space(1))) void*)(gptr),                 \
        (__attribute__((address_space(3))) void*)(lptr), 16, 0, 0)

// ---------- fp32 -> bf16 convert, all 4 weight matrices in one launch ----------
__global__ __launch_bounds__(256) void cvt4_kernel(
    const float* __restrict__ w0, const float* __restrict__ w1,
    const float* __restrict__ w2, const float* __restrict__ w3,
    unsigned short* __restrict__ dst)
{
    const int i = blockIdx.x * 256 + threadIdx.x;   // 0..196607
    const float* s; int off;
    if      (i <  49152) { s = w0; off = 0; }
    else if (i <  65536) { s = w1; off = 49152; }
    else if (i < 131072) { s = w2; off = 65536; }
    else                 { s = w3; off = 131072; }
    f32x4 v = ((const f32x4*)s)[i - off];
    ushort4 o;
    o.x = f2bf(v.x); o.y = f2bf(v.y); o.z = f2bf(v.z); o.w = f2bf(v.w);
    ((ushort4*)dst)[i] = o;
}

// ---------- LayerNorm (LN1): fp32 in -> bf16 out, one wave per token ----------
__global__ __launch_bounds__(256) void ln_kernel(
    const float* __restrict__ x, const float* __restrict__ g,
    const float* __restrict__ b, unsigned short* __restrict__ y)
{
    const int lane = threadIdx.x & 63, wave = threadIdx.x >> 6;
    const size_t tok = (size_t)blockIdx.x * 4 + wave;
    f32x4 v = *(const f32x4*)(x + tok * 256 + lane * 4);
    float s = v.x + v.y + v.z + v.w;
    float q = v.x * v.x + v.y * v.y + v.z * v.z + v.w * v.w;
#pragma unroll
    for (int o = 32; o; o >>= 1) {
        s += __shfl_xor(s, o, 64);
        q += __shfl_xor(q, o, 64);
    }
    float mean = s * (1.f / 256.f);
    float var  = q * (1.f / 256.f) - mean * mean;
    float rstd = rsqrtf(var + 1e-5f);
    f32x4 gr = *(const f32x4*)(g + lane * 4);
    f32x4 br = *(const f32x4*)(b + lane * 4);
    ushort4 o4;
    o4.x = f2bf((v.x - mean) * rstd * gr.x + br.x);
    o4.y = f2bf((v.y - mean) * rstd * gr.y + br.y);
    o4.z = f2bf((v.z - mean) * rstd * gr.z + br.z);
    o4.w = f2bf((v.w - mean) * rstd * gr.w + br.w);
    *(ushort4*)(y + tok * 256 + lane * 4) = o4;
}

// ---------- GEMM (phase A: qkv) ----------
template <int RELU, int HASRES, int OUTF32>
__global__ __launch_bounds__(256) void gemm_bt(
    const unsigned short* __restrict__ A,    // [M,K] bf16
    const unsigned short* __restrict__ W,    // [N,K] bf16
    const float* __restrict__ bias,          // [N]   fp32
    const float* res,                        // [M,N] fp32 or null
    void* Cv,                                // [M,N] bf16 or fp32
    int M, int N, int K, int nby)
{
    __shared__ __align__(16) unsigned short As[128 * 64];
    __shared__ __align__(16) unsigned short Bs[128 * 64];

    const int t    = threadIdx.x;
    const int id   = blockIdx.x;
    const int xcd  = id & 7;
    const int sl   = id >> 3;
    const int by   = sl % nby;
    const int bx   = (sl / nby) * 8 + xcd;
    const int m0   = bx * 128;
    const int n0   = by * 128;
    const int lane = t & 63;
    const int wave = t >> 6;
    const int wm = wave & 1, wn = wave >> 1;
    const int lr = lane & 15, kc = lane >> 4;

    f32x4 acc[4][4] = {};

    const int rA   = t >> 3;                       // 0..31
    const int gcol = ((t & 7) ^ (rA & 7)) * 8;
    const unsigned short* gA = A + (size_t)(m0 + rA) * K + gcol;
    const unsigned short* gB = W + (size_t)(n0 + rA) * K + gcol;

    for (int k0 = 0; k0 < K; k0 += 64) {
#pragma unroll
        for (int w = 0; w < 4; ++w) {
            GLL16(gA + (size_t)(w * 32) * K + k0, &As[(w * 256 + t) * 8]);
            GLL16(gB + (size_t)(w * 32) * K + k0, &Bs[(w * 256 + t) * 8]);
        }
        __syncthreads();

#pragma unroll
        for (int hh = 0; hh < 2; ++hh) {
            bf16x8 af[4], bf[4];
#pragma unroll
            for (int i = 0; i < 4; ++i) {
                const int ra = wm * 64 + i * 16 + lr;
                const int rb = wn * 64 + i * 16 + lr;
                af[i] = *(const bf16x8*)&As[ra * 64 + ((hh * 4 + kc) ^ (ra & 7)) * 8];
                bf[i] = *(const bf16x8*)&Bs[rb * 64 + ((hh * 4 + kc) ^ (rb & 7)) * 8];
            }
#pragma unroll
            for (int i = 0; i < 4; ++i)
#pragma unroll
                for (int j = 0; j < 4; ++j)
                    acc[i][j] = __builtin_amdgcn_mfma_f32_16x16x32_bf16(
                        af[i], bf[j], acc[i][j], 0, 0, 0);
        }
        __syncthreads();
    }

    float* Cf = (float*)Cv;
    unsigned short* Cb = (unsigned short*)Cv;
    const int row0 = m0 + wm * 64;
    const int col0 = n0 + wn * 64;
    const int cl = lane & 15;
    const int rq = (lane >> 4) * 4;
#pragma unroll
    for (int i = 0; i < 4; ++i) {
#pragma unroll
        for (int j = 0; j < 4; ++j) {
            const int col = col0 + j * 16 + cl;
            const float bv = bias[col];
#pragma unroll
            for (int r = 0; r < 4; ++r) {
                const int row = row0 + i * 16 + rq + r;
                float v = acc[i][j][r] + bv;
                if (RELU) v = fmaxf(v, 0.f);
                const size_t o = (size_t)row * N + col;
                if (HASRES) v += res[o];
                if (OUTF32) Cf[o] = v;
                else        Cb[o] = f2bf(v);
            }
        }
    }
}

// ---------- Fused per-token head-mix + proj GEMM + residual (NEW, R4) ----------
// The "attention" is per-token (8x8 head mix), so it fuses into the proj
// GEMM's A-tile construction: 128-token tile, 512 threads (8 waves, 2x4).
// Phase 1: 16 headmix passes (one token per wave, verbatim per-token math)
//   write the att tile into U (swizzled A layout). proj_w K-chunks 0,1 staged
//   concurrently via GLL16.
// Phase 2: register-cache A fragments; 4 x (K=64) GEMM chunks, Wk double-
//   buffered; 1 barrier per chunk (full-drain __syncthreads, the R1-proven
//   discipline -- counted-vmcnt/8-phase measured SLOWER at 2 waves/SIMD).
// Kills the attn_headmix kernel + the 67 MB att round-trip.
__global__ __launch_bounds__(512, 2) void proj_attn(
    const unsigned short* __restrict__ qkv,  // [M,768] bf16
    const unsigned short* __restrict__ wp,   // [256,256] bf16 (proj_w)
    const float* __restrict__ bias,          // [256]
    const float* __restrict__ res,           // [M,256] fp32 (x)
    float* __restrict__ out)                 // [M,256] fp32 (xo)
{
    __shared__ __align__(16) unsigned short U[128 * 256];   // 64 KB att tile
    __shared__ __align__(16) unsigned short Wk[2][16384];   // 2 x 32 KB

    const int t = threadIdx.x;               // 0..511
    const int lane = t & 63, wave = t >> 6;
    const int m0 = blockIdx.x * 128;
    const int lr = lane & 15, kc = lane >> 4;
    const int cl = lane & 15, rq = (lane >> 4) * 4;
    const int wm = wave & 1, wn = wave >> 1; // wn in 0..3

    // W staging indices (identical scheme to ffn_fused W2)
    const int r2b = t >> 3;                  // 0..63
    const int gc2 = (t & 7) ^ (r2b & 7);

    #define STAGE_WP(kc4, Wt)                                                  \
        do {                                                                   \
            _Pragma("unroll")                                                  \
            for (int j = 0; j < 4; ++j)                                        \
                GLL16(wp + (size_t)(j * 64 + r2b) * 256 + (kc4) * 64 + gc2 * 8,\
                      &(Wt)[(j * 512 + t) * 8]);                               \
        } while (0)

    STAGE_WP(0, Wk[0]);
    STAGE_WP(1, Wk[1]);

    // ---- phase 1: head-mix, one token per wave per pass -> U (swizzled) ----
    const int h = lane >> 3, g = lane & 7;
    for (int p = 0; p < 16; ++p) {
        const int row = p * 8 + wave;        // token-in-tile 0..127
        const unsigned short* base = qkv + (size_t)(m0 + row) * 768;

        float s = 0.f;
#pragma unroll
        for (int d8 = 0; d8 < 4; ++d8) {
            ushort4 qa = *(const ushort4*)(base + h * 32 + d8 * 8);
            ushort4 qb = *(const ushort4*)(base + h * 32 + d8 * 8 + 4);
            ushort4 ka = *(const ushort4*)(base + 256 + g * 32 + d8 * 8);
            ushort4 kb = *(const ushort4*)(base + 256 + g * 32 + d8 * 8 + 4);
            s += bf2f(qa.x) * bf2f(ka.x) + bf2f(qa.y) * bf2f(ka.y)
               + bf2f(qa.z) * bf2f(ka.z) + bf2f(qa.w) * bf2f(ka.w)
               + bf2f(qb.x) * bf2f(kb.x) + bf2f(qb.y) * bf2f(kb.y)
               + bf2f(qb.z) * bf2f(kb.z) + bf2f(qb.w) * bf2f(kb.w);
        }
        s *= 0.17677669529663687f;

        float mx = s;
#pragma unroll
        for (int o = 1; o < 8; o <<= 1) mx = fmaxf(mx, __shfl_xor(mx, o, 64));
        float e = __expf(s - mx);
        float sum = e;
#pragma unroll
        for (int o = 1; o < 8; o <<= 1) sum += __shfl_xor(sum, o, 64);
        const float a = e / sum;

        float o0 = 0.f, o1 = 0.f, o2 = 0.f, o3 = 0.f;
#pragma unroll
        for (int gg = 0; gg < 8; ++gg) {
            const float ag = __shfl(a, (lane & 56) | gg, 64);
            ushort4 vv = *(const ushort4*)(base + 512 + gg * 32 + g * 4);
            o0 += ag * bf2f(vv.x);
            o1 += ag * bf2f(vv.y);
            o2 += ag * bf2f(vv.z);
            o3 += ag * bf2f(vv.w);
        }
        // lane owns channels lane*4..+3 (= h*32 + g*4). Swizzled A layout:
        // 16B chunk gcu = lane>>1, half = lane&1; sc = swz(gcu, row).
        const int gcu = lane >> 1;
        const int sc = (gcu & ~7) | ((gcu & 7) ^ (row & 7));
        ushort4 ov;
        ov.x = f2bf(o0); ov.y = f2bf(o1); ov.z = f2bf(o2); ov.w = f2bf(o3);
        *(ushort4*)&U[row * 256 + sc * 8 + (lane & 1) * 4] = ov;
    }
    __syncthreads();   // U ready; Wk[0]/Wk[1] landed (full drain)

    // ---- register-cache A fragments (rows wm*64..+63, all K=256) ----
    bf16x8 afr[4][8];
#pragma unroll
    for (int i = 0; i < 4; ++i) {
        const int ra = wm * 64 + i * 16 + lr;
#pragma unroll
        for (int ks = 0; ks < 8; ++ks) {
            const int c = ks * 4 + kc;
            afr[i][ks] = *(const bf16x8*)
                &U[ra * 256 + ((c & ~7) | ((c & 7) ^ (ra & 7))) * 8];
        }
    }

    // ---- phase 2: 4 K-chunks of 64, Wk double-buffered ----
    f32x4 acc[4][4] = {};
    for (int c4 = 0; c4 < 4; ++c4) {
        if (c4 >= 2) __syncthreads();        // staged chunk c4 landed
        const unsigned short* Wc = Wk[c4 & 1];
#pragma unroll
        for (int kk = 0; kk < 2; ++kk) {
            const int c = kk * 4 + kc;       // 16B col-chunk within K=64
            bf16x8 bw[4];
#pragma unroll
            for (int j = 0; j < 4; ++j) {
                const int rb = wn * 64 + j * 16 + lr;
                bw[j] = *(const bf16x8*)&Wc[rb * 64 + ((c ^ (rb & 7)) * 8)];
            }
#pragma unroll
            for (int i = 0; i < 4; ++i)
#pragma unroll
                for (int j = 0; j < 4; ++j)
                    acc[i][j] = __builtin_amdgcn_mfma_f32_16x16x32_bf16(
                        afr[i][c4 * 2 + kk], bw[j], acc[i][j], 0, 0, 0);
        }
        if (c4 < 2) {
            __syncthreads();                 // all waves done with Wk[c4&1]
            STAGE_WP(c4 + 2, Wk[c4 & 1]);
        }
    }

    // ---- epilogue: + bias + residual, fp32 out ----
#pragma unroll
    for (int i = 0; i < 4; ++i)
#pragma unroll
        for (int j = 0; j < 4; ++j) {
            const int col = wn * 64 + j * 16 + cl;
            const float bv = bias[col];
#pragma unroll
            for (int r = 0; r < 4; ++r) {
                const int row = m0 + wm * 64 + i * 16 + rq + r;
                const size_t o = (size_t)row * 256 + col;
                out[o] = acc[i][j][r] + bv + res[o];
            }
        }
    #undef STAGE_WP
}

// ---------- Fused LN2 + FFN1(relu) + FFN2 + residual, in-place on xo ----------
// REVERTED to the R1 structure (measured 118 us; R2 counted-vmcnt = 122,
// R3 8-phase = 142 -- fine-grained scheduling hurts at 2 waves/SIMD).
// Single barrier per hidden chunk; Hs double-buffered; swapped h-phase MFMA
// operands (packed ds_write_b64 Hs stores); setprio around MFMA clusters.
// Region R(hc): { stage W1(hc+2), stage W2(hc+1), h(hc+1)->Hs[nxt],
//                 out(hc)<-Hs[cur], __syncthreads }.
__global__ __launch_bounds__(512, 2) void ffn_fused(
    float* xo,                               // [M,256] fp32, read + written
    const float* __restrict__ ln2_g, const float* __restrict__ ln2_b,
    const unsigned short* __restrict__ w1,   // [1024,256] bf16
    const float* __restrict__ b1p,           // [1024]
    const unsigned short* __restrict__ w2,   // [256,1024] bf16
    const float* __restrict__ b2p)           // [256]
{
    __shared__ __align__(16) unsigned short U[32768];      // 64 KB: As, then W1b|W2b
    __shared__ __align__(16) unsigned short W1a[16384];    // 32 KB
    __shared__ __align__(16) unsigned short W2a[16384];    // 32 KB
    __shared__ __align__(16) unsigned short Hs[2][8192];   // 2 x 16 KB, swizzled

    unsigned short* const W1b = U;
    unsigned short* const W2b = U + 16384;

    const int t = threadIdx.x;               // 0..511
    const int lane = t & 63, wave = t >> 6;
    const int m0 = blockIdx.x * 128;
    const int lr = lane & 15, kc = lane >> 4;
    const int cl = lane & 15, rq = (lane >> 4) * 4;
    const int wm = wave & 1, wn = wave >> 1; // wn in 0..3

    // staging index precompute (j-invariant parts)
    const int r1b = t >> 5;                  // W1 row base 0..15
    const int sc1 = t & 31;
    const int gc1 = (sc1 & ~7) | ((sc1 & 7) ^ (r1b & 7));
    const int r2b = t >> 3;                  // W2 row base 0..63
    const int gc2 = (t & 7) ^ (r2b & 7);

    #define STAGE_W1(hp, W1t)                                                  \
        do {                                                                   \
            _Pragma("unroll")                                                  \
            for (int j = 0; j < 4; ++j)                                        \
                GLL16(w1 + (size_t)((hp) * 64 + j * 16 + r1b) * 256 + gc1 * 8, \
                      &(W1t)[(j * 512 + t) * 8]);                              \
        } while (0)
    #define STAGE_W2(hp, W2t)                                                  \
        do {                                                                   \
            _Pragma("unroll")                                                  \
            for (int j = 0; j < 4; ++j)                                        \
                GLL16(w2 + (size_t)(j * 64 + r2b) * 1024 + (hp) * 64 + gc2 * 8,\
                      &(W2t)[(j * 512 + t) * 8]);                              \
        } while (0)

    STAGE_W1(0, W1a);
    STAGE_W2(0, W2a);

    // ---- phase 0: LN2 of the 128-row tile -> bf16 As in U (swizzled) ----
    {
        const int row0 = t >> 2;             // 0..127
        const int seg  = t & 3;              // 64-float segment
        const float* xrp = xo + (size_t)(m0 + row0) * 256 + seg * 64;
        f32x4 xv[16];
#pragma unroll
        for (int i = 0; i < 16; ++i) xv[i] = ((const f32x4*)xrp)[i];
        float s = 0.f, q = 0.f;
#pragma unroll
        for (int i = 0; i < 16; ++i) {
            s += xv[i].x + xv[i].y + xv[i].z + xv[i].w;
            q += xv[i].x * xv[i].x + xv[i].y * xv[i].y
               + xv[i].z * xv[i].z + xv[i].w * xv[i].w;
        }
        s += __shfl_xor(s, 1, 64); q += __shfl_xor(q, 1, 64);
        s += __shfl_xor(s, 2, 64); q += __shfl_xor(q, 2, 64);
        const float mean = s * (1.f / 256.f);
        const float rstd = rsqrtf(q * (1.f / 256.f) - mean * mean + 1e-5f);
#pragma unroll
        for (int c8 = 0; c8 < 8; ++c8) {
            const f32x4 g0 = ((const f32x4*)(ln2_g + seg * 64 + c8 * 8))[0];
            const f32x4 g1 = ((const f32x4*)(ln2_g + seg * 64 + c8 * 8))[1];
            const f32x4 bb0 = ((const f32x4*)(ln2_b + seg * 64 + c8 * 8))[0];
            const f32x4 bb1 = ((const f32x4*)(ln2_b + seg * 64 + c8 * 8))[1];
            const f32x4 a0 = xv[c8 * 2], a1 = xv[c8 * 2 + 1];
            ushort8 o;
            o[0] = f2bf((a0.x - mean) * rstd * g0.x + bb0.x);
            o[1] = f2bf((a0.y - mean) * rstd * g0.y + bb0.y);
            o[2] = f2bf((a0.z - mean) * rstd * g0.z + bb0.z);
            o[3] = f2bf((a0.w - mean) * rstd * g0.w + bb0.w);
            o[4] = f2bf((a1.x - mean) * rstd * g1.x + bb1.x);
            o[5] = f2bf((a1.y - mean) * rstd * g1.y + bb1.y);
            o[6] = f2bf((a1.z - mean) * rstd * g1.z + bb1.z);
            o[7] = f2bf((a1.w - mean) * rstd * g1.w + bb1.w);
            const int gc = seg * 8 + c8;     // global chunk 0..31
            const int sc = (gc & ~7) | ((gc & 7) ^ (row0 & 7));
            *(ushort8*)&U[row0 * 256 + sc * 8] = o;
        }
    }
    __syncthreads();   // As ready; W(0) landed (vmcnt drained)

    // ---- register-cache this wave's A fragments (rows wm*64..+63, all K) ----
    bf16x8 afr[4][8];
#pragma unroll
    for (int i = 0; i < 4; ++i) {
        const int ra = wm * 64 + i * 16 + lr;
#pragma unroll
        for (int ks = 0; ks < 8; ++ks) {
            const int c = ks * 4 + kc;
            afr[i][ks] = *(const bf16x8*)
                &U[ra * 256 + ((c & ~7) | ((c & 7) ^ (ra & 7))) * 8];
        }
    }
    __syncthreads();   // all waves done reading U -> it becomes W buffer B
    STAGE_W1(1, W1b);  // W2(1) staged inside R(0)

    f32x4 acc[4][4] = {};                    // out tile: rows wm*64, cols wn*64

    // ---- h-phase for chunk hcv: mfma(W1frag, tokenfrag) -> Hs[buf] ----
    // lane holds: token col = wm*64+i*16+cl, hidden rows = wn*16+rq+{0..3}
    // Hs swizzle: 16B-slot s' = s ^ (token&7), row stride 64 ushorts.
    #define HPHASE(hcv, W1c, Hbuf)                                             \
        do {                                                                   \
            f32x4 acch[4] = {};                                                \
            __builtin_amdgcn_s_setprio(1);                                     \
            _Pragma("unroll")                                                  \
            for (int ks = 0; ks < 8; ++ks) {                                   \
                const int c = ks * 4 + kc;                                     \
                const int rb = wn * 16 + lr;                                   \
                const bf16x8 bfr = *(const bf16x8*)                            \
                    &(W1c)[rb * 256 + ((c & ~7) | ((c & 7) ^ (rb & 7))) * 8];  \
                _Pragma("unroll")                                              \
                for (int i = 0; i < 4; ++i)                                    \
                    acch[i] = __builtin_amdgcn_mfma_f32_16x16x32_bf16(         \
                        bfr, afr[i][ks], acch[i], 0, 0, 0);                    \
            }                                                                  \
            __builtin_amdgcn_s_setprio(0);                                     \
            const f32x4 bv = *(const f32x4*)(b1p + (hcv) * 64 + wn * 16 + rq); \
            const int sbase = wn * 2 + (rq >> 3);                              \
            _Pragma("unroll")                                                  \
            for (int i = 0; i < 4; ++i) {                                      \
                const int tok = wm * 64 + i * 16 + cl;                         \
                ushort4 o;                                                     \
                o.x = f2bf(fmaxf(acch[i][0] + bv.x, 0.f));                     \
                o.y = f2bf(fmaxf(acch[i][1] + bv.y, 0.f));                     \
                o.z = f2bf(fmaxf(acch[i][2] + bv.z, 0.f));                     \
                o.w = f2bf(fmaxf(acch[i][3] + bv.w, 0.f));                     \
                *(ushort4*)&(Hbuf)[tok * 64 + ((sbase ^ (tok & 7)) * 8)        \
                                   + (rq & 4)] = o;                            \
            }                                                                  \
        } while (0)

    // ---- out-phase for chunk hcv: acc += Hs[buf] @ W2c^T (k = 64) ----
    #define OPHASE(W2c, Hbuf)                                                  \
        do {                                                                   \
            _Pragma("unroll")                                                  \
            for (int ks = 0; ks < 2; ++ks) {                                   \
                const int c = ks * 4 + kc;                                     \
                bf16x8 bw[4];                                                  \
                _Pragma("unroll")                                              \
                for (int j = 0; j < 4; ++j) {                                  \
                    const int rb = wn * 64 + j * 16 + lr;                      \
                    bw[j] = *(const bf16x8*)                                   \
                        &(W2c)[rb * 64 + ((c ^ (rb & 7)) * 8)];                \
                }                                                              \
                __builtin_amdgcn_s_setprio(1);                                 \
                _Pragma("unroll")                                              \
                for (int i = 0; i < 4; ++i) {                                  \
                    const int ra = wm * 64 + i * 16 + lr;                      \
                    const bf16x8 ah = *(const bf16x8*)                         \
                        &(Hbuf)[ra * 64 + ((c ^ (ra & 7)) * 8)];               \
                    _Pragma("unroll")                                          \
                    for (int j = 0; j < 4; ++j)                                \
                        acc[i][j] = __builtin_amdgcn_mfma_f32_16x16x32_bf16(   \
                            ah, bw[j], acc[i][j], 0, 0, 0);                    \
                }                                                              \
                __builtin_amdgcn_s_setprio(0);                                 \
            }                                                                  \
        } while (0)

    HPHASE(0, W1a, Hs[0]);
    __syncthreads();   // Hs[0] ready; W1(1) landed

    for (int hc = 0; hc < 16; ++hc) {
        // stages first: W1 two ahead (into chunk-hc's buffer, freed last
        // region by h(hc)); W2 one ahead (into chunk-(hc-1)'s buffer, freed
        // last region by out(hc-1)).
        if (hc < 14) STAGE_W1(hc + 2, (hc & 1) ? W1b : W1a);
        if (hc < 15) STAGE_W2(hc + 1, (hc & 1) ? W2a : W2b);
        if (hc < 15) HPHASE(hc + 1, (hc & 1) ? W1a : W1b, Hs[(hc + 1) & 1]);
        OPHASE((hc & 1) ? W2b : W2a, Hs[hc & 1]);
        __syncthreads();   // Hs[nxt] + staged W ready for next region
    }

    // ---- epilogue: + b2 + residual(xo), write fp32 in place ----
    const int rqe = (lane >> 4) * 4;
#pragma unroll
    for (int i = 0; i < 4; ++i)
#pragma unroll
        for (int j = 0; j < 4; ++j) {
            const int col = wn * 64 + j * 16 + cl;
            const float bv = b2p[col];
#pragma unroll
            for (int r = 0; r < 4; ++r) {
                const int row = m0 + wm * 64 + i * 16 + rqe + r;
                const size_t o = (size_t)row * 256 + col;
                xo[o] = acc[i][j][r] + bv + xo[o];
            }
        }
    #undef STAGE_W1
    #undef STAGE_W2
    #undef HPHASE
    #undef OPHASE
}

// ---------- launch ----------
// fp32 I/O, bf16 internal, fp32 residual trunk on d_out.
// ws layout (ushort elems): weights [0,786432); xn [1M,17M); qkvb [33M,81M).
extern "C" void kernel_launch(void* const* d_in, const int* in_sizes, int n_in,
                              void* d_out, int out_size, void* d_ws, size_t ws_size,
                              hipStream_t stream)
{
    const float* x      = (const float*)d_in[0];
    const float* ln1_g  = (const float*)d_in[1];
    const float* ln1_b  = (const float*)d_in[2];
    const float* qkv_w  = (const float*)d_in[3];
    const float* qkv_b  = (const float*)d_in[4];
    const float* proj_w = (const float*)d_in[5];
    const float* proj_b = (const float*)d_in[6];
    const float* ln2_g  = (const float*)d_in[7];
    const float* ln2_b  = (const float*)d_in[8];
    const float* ffn_w1 = (const float*)d_in[9];
    const float* ffn_b1 = (const float*)d_in[10];
    const float* ffn_w2 = (const float*)d_in[11];
    const float* ffn_b2 = (const float*)d_in[12];
    float* xo = (float*)d_out;            // fp32 trunk + final out

    const int M = 65536;
    const size_t MEG = 1024 * 1024;
    unsigned short* ws = (unsigned short*)d_ws;
    unsigned short* qkv_wb  = ws;                   // 196608
    unsigned short* proj_wb = ws + 196608;          // 65536
    unsigned short* ffn_w1b = ws + 262144;          // 262144
    unsigned short* ffn_w2b = ws + 524288;          // 262144
    unsigned short* xn   = ws + 1 * MEG;            // [M,256]
    unsigned short* qkvb = ws + 33 * MEG;           // [M,768]

    cvt4_kernel<<<768, 256, 0, stream>>>(qkv_w, proj_w, ffn_w1, ffn_w2, ws);

    ln_kernel<<<M / 4, 256, 0, stream>>>(x, ln1_g, ln1_b, xn);
    gemm_bt<0, 0, 0><<<3072, 256, 0, stream>>>(
        xn, qkv_wb, qkv_b, nullptr, qkvb, M, 768, 256, 6);
    proj_attn<<<M / 128, 512, 0, stream>>>(
        qkvb, proj_wb, proj_b, x, xo);
    ffn_fused<<<M / 128, 512, 0, stream>>>(
        xo, ln2_g, ln2_b, ffn_w1b, ffn_b1, ffn_w2b, ffn_b2);
}